// Round 1
// baseline (362.329 us; speedup 1.0000x reference)
//
#include <hip/hip_runtime.h>

// Problem: VQ — N=262144 vectors (64x4096), D=64, K=512 codewords, all fp32.
// out layout (float32): quantized[16777216] | indices[262144] (as float) | loss[1]

#define NVEC  262144
#define DDIM  64
#define KCW   512
#define BM    64      // vectors per block
#define BN    128     // codeword chunk in LDS
#define TM    4       // rows per thread
#define TN    8       // codewords per thread (n = tx + 16*j)
#define APAD  68      // LDS row stride (floats): 16B-aligned, breaks pow2 bank stride
#define BPAD  68
#define LOSS_SCALE (0.25f / 16777216.0f)   // COMMITMENT_COST / (N*D)

__global__ void csq_zero_kernel(const float* __restrict__ cw,
                                float* __restrict__ csq,
                                float* __restrict__ loss_slot) {
    int n = blockIdx.x * blockDim.x + threadIdx.x;
    if (n < KCW) {
        float s = 0.f;
        const float* r = cw + n * DDIM;
        #pragma unroll 8
        for (int d = 0; d < DDIM; ++d) { float v = r[d]; s += v * v; }
        csq[n] = s;
    }
    if (n == 0) *loss_slot = 0.f;   // d_out is poisoned before every launch
}

__global__ __launch_bounds__(256, 3)
void vq_kernel(const float* __restrict__ x, const float* __restrict__ cw,
               const float* __restrict__ csq,
               float* __restrict__ out_q, float* __restrict__ out_idx,
               float* __restrict__ out_loss) {
    __shared__ float A[BM][APAD];     // input tile, row-major
    __shared__ float B[BN][BPAD];     // codeword chunk, row-major
    __shared__ float xsq[BM];
    __shared__ int   win[BM];
    __shared__ float red[4];

    const int tid = threadIdx.x;
    const int tx = tid & 15;          // codeword group
    const int ty = tid >> 4;          // row group (0..15), rows ty*4..ty*4+3
    const long base_row = (long)blockIdx.x * BM;

    // ---- stage A: 64 rows x 64 floats (16 KB), coalesced float4 ----
    {
        int m  = tid >> 2;
        int kq = (tid & 3) << 4;
        const float4* g = (const float4*)(x + (base_row + m) * DDIM + kq);
        float4 v0 = g[0], v1 = g[1], v2 = g[2], v3 = g[3];
        *(float4*)&A[m][kq + 0]  = v0;
        *(float4*)&A[m][kq + 4]  = v1;
        *(float4*)&A[m][kq + 8]  = v2;
        *(float4*)&A[m][kq + 12] = v3;
    }
    __syncthreads();

    // ---- x_sq per row (once per block) ----
    if (tid < BM) {
        float s = 0.f;
        #pragma unroll
        for (int k = 0; k < DDIM; k += 4) {
            float4 v = *(const float4*)&A[tid][k];
            s += v.x * v.x; s += v.y * v.y; s += v.z * v.z; s += v.w * v.w;
        }
        xsq[tid] = s;
    }

    float best[TM];
    int   bidx[TM];
    #pragma unroll
    for (int i = 0; i < TM; ++i) { best[i] = 3.402823466e38f; bidx[i] = 0; }

    for (int ch = 0; ch < KCW / BN; ++ch) {
        __syncthreads();   // previous chunk's B reads done (also covers xsq publish)
        // ---- stage B chunk: 128 codewords x 64 floats (32 KB) ----
        {
            int n  = tid >> 1;
            int kq = (tid & 1) << 5;
            const float4* g = (const float4*)(cw + (ch * BN + n) * DDIM + kq);
            #pragma unroll
            for (int t = 0; t < 8; ++t) *(float4*)&B[n][kq + 4 * t] = g[t];
        }
        __syncthreads();

        float acc[TM][TN];
        #pragma unroll
        for (int i = 0; i < TM; ++i)
            #pragma unroll
            for (int j = 0; j < TN; ++j) acc[i][j] = 0.f;

        #pragma unroll 4
        for (int kk = 0; kk < DDIM; kk += 4) {
            float4 a[TM];
            #pragma unroll
            for (int i = 0; i < TM; ++i)
                a[i] = *(const float4*)&A[ty * TM + i][kk];
            #pragma unroll
            for (int j = 0; j < TN; ++j) {
                float4 b = *(const float4*)&B[tx + 16 * j][kk];
                #pragma unroll
                for (int i = 0; i < TM; ++i) {
                    acc[i][j] += a[i].x * b.x;
                    acc[i][j] += a[i].y * b.y;
                    acc[i][j] += a[i].z * b.z;
                    acc[i][j] += a[i].w * b.w;
                }
            }
        }

        // ---- epilogue: distances + running argmin (n ascending => first-min kept) ----
        #pragma unroll
        for (int j = 0; j < TN; ++j) {
            int n = ch * BN + 16 * j + tx;
            float cs = csq[n];            // L1/L2-cached
            #pragma unroll
            for (int i = 0; i < TM; ++i) {
                float dist = (xsq[ty * TM + i] - 2.0f * acc[i][j]) + cs;
                if (dist < best[i]) { best[i] = dist; bidx[i] = n; }
            }
        }
    }

    // ---- argmin reduce across the 16 tx lanes (within-wave shuffles) ----
    #pragma unroll
    for (int i = 0; i < TM; ++i) {
        float d = best[i]; int ix = bidx[i];
        #pragma unroll
        for (int off = 8; off > 0; off >>= 1) {
            float d2 = __shfl_down(d, off, 16);
            int   i2 = __shfl_down(ix, off, 16);
            if (d2 < d || (d2 == d && i2 < ix)) { d = d2; ix = i2; }
        }
        if (tx == 0) {
            int m = ty * TM + i;
            win[m] = ix;
            out_idx[base_row + m] = (float)ix;
        }
    }
    __syncthreads();

    // ---- write quantized + elementwise commitment loss ----
    float ls = 0.f;
    {
        int m  = tid >> 2;
        int kq = (tid & 3) << 4;
        int w  = win[m];
        const float4* g = (const float4*)(cw + w * DDIM + kq);   // 128KB table, L2-hot
        float4* o = (float4*)(out_q + (base_row + m) * DDIM + kq);
        #pragma unroll
        for (int t = 0; t < 4; ++t) {
            float4 q  = g[t];
            float4 xv = *(const float4*)&A[m][kq + 4 * t];
            o[t] = q;
            float dx = q.x - xv.x, dy = q.y - xv.y;
            float dz = q.z - xv.z, dw = q.w - xv.w;
            ls += dx * dx; ls += dy * dy; ls += dz * dz; ls += dw * dw;
        }
    }
    #pragma unroll
    for (int off = 32; off > 0; off >>= 1) ls += __shfl_down(ls, off, 64);
    if ((tid & 63) == 0) red[tid >> 6] = ls;
    __syncthreads();
    if (tid == 0) {
        float s = (red[0] + red[1]) + (red[2] + red[3]);
        atomicAdd(out_loss, s * LOSS_SCALE);
    }
}

extern "C" void kernel_launch(void* const* d_in, const int* in_sizes, int n_in,
                              void* d_out, int out_size, void* d_ws, size_t ws_size,
                              hipStream_t stream) {
    const float* x  = (const float*)d_in[0];   // (64,4096,64) fp32
    const float* cw = (const float*)d_in[1];   // (512,64) fp32
    float* out      = (float*)d_out;
    float* out_q    = out;                      // 16777216
    float* out_idx  = out + 16777216;           // 262144
    float* out_loss = out + 16777216 + 262144;  // 1
    float* csq      = (float*)d_ws;             // 512 floats scratch

    csq_zero_kernel<<<8, 64, 0, stream>>>(cw, csq, out_loss);
    vq_kernel<<<NVEC / BM, 256, 0, stream>>>(x, cw, csq, out_q, out_idx, out_loss);
}